// Round 3
// baseline (494.514 us; speedup 1.0000x reference)
//
#include <hip/hip_runtime.h>
#include <hip/hip_bf16.h>
#include <cstdint>
#include <cstddef>

#define NB     2048
#define DIM    16384
#define NE     512
#define NQ     (NB * DIM)
#define NENC   (NB * NE)
#define SPLITS 16
#define NKT    (DIM / 32)       // 512 k-chunks of 32

typedef float  f32x4  __attribute__((ext_vector_type(4)));
typedef short  short8 __attribute__((ext_vector_type(8)));

// ---------- bf16 split helpers (RNE) ----------
__device__ inline unsigned short f2bf_rne(float f) {
  unsigned u = __float_as_uint(f);
  u += 0x7fffu + ((u >> 16) & 1u);
  return (unsigned short)(u >> 16);
}
__device__ inline float bf2f(unsigned short h) {
  return __uint_as_float(((unsigned)h) << 16);
}

// XOR swizzle inside a [128][32]-bf16 (64 B/row) tile.
__device__ inline int swz(int row, int kByte) {
  return row * 64 + (kByte ^ (((row >> 1) & 3) << 4));
}

__device__ inline void write_split(unsigned short* hiArr, unsigned short* loArr,
                                   int row, int kc, float4 v) {
  float f0 = v.x, f1 = v.y, f2 = v.z, f3 = v.w;
  unsigned short h0 = f2bf_rne(f0), h1 = f2bf_rne(f1), h2 = f2bf_rne(f2), h3 = f2bf_rne(f3);
  unsigned short l0 = f2bf_rne(f0 - bf2f(h0));
  unsigned short l1 = f2bf_rne(f1 - bf2f(h1));
  unsigned short l2 = f2bf_rne(f2 - bf2f(h2));
  unsigned short l3 = f2bf_rne(f3 - bf2f(h3));
  int off = swz(row, kc * 2);
  uint2 hv, lv;
  hv.x = (unsigned)h0 | ((unsigned)h1 << 16);
  hv.y = (unsigned)h2 | ((unsigned)h3 << 16);
  lv.x = (unsigned)l0 | ((unsigned)l1 << 16);
  lv.y = (unsigned)l2 | ((unsigned)l3 << 16);
  *(uint2*)((char*)hiArr + off) = hv;
  *(uint2*)((char*)loArr + off) = lv;
}

__device__ __forceinline__ void gload16(const void* g, void* l) {
  __builtin_amdgcn_global_load_lds(
      (const __attribute__((address_space(1))) unsigned int*)(unsigned long long)(uintptr_t)g,
      (__attribute__((address_space(3))) unsigned int*)(unsigned int)(uintptr_t)l,
      16, 0, 0);
}

__device__ inline float blockReduceSum(float v) {
  #pragma unroll
  for (int o = 32; o > 0; o >>= 1) v += __shfl_down(v, o, 64);
  __shared__ float tmp[4];
  int w = threadIdx.x >> 6, l = threadIdx.x & 63;
  if (l == 0) tmp[w] = v;
  __syncthreads();
  float r = 0.f;
  if (threadIdx.x == 0) r = tmp[0] + tmp[1] + tmp[2] + tmp[3];
  return r;
}

// =================== FAST PATH ===================

// ---------- P0a: x -> swizzled bf16 hi/lo panels + row norms xN ----------
// One wave per row; 512 blocks x 4 waves. Lane reads 64 float4 (1KB/wave/iter).
__global__ void k_prepA(const float* __restrict__ x,
                        unsigned short* __restrict__ AhP, unsigned short* __restrict__ AlP,
                        float* __restrict__ xN) {
  int t = threadIdx.x, lane = t & 63, w = t >> 6;
  int row = blockIdx.x * 4 + w;
  const float* src = x + (size_t)row * DIM;
  int p = row >> 7, rloc = row & 127;
  int kc = (lane & 7) * 4;
  float s = 0.f;
  #pragma unroll 8
  for (int i = 0; i < 64; ++i) {
    int kk = lane * 4 + i * 256;
    float4 v = *(const float4*)(src + kk);
    s += v.x * v.x + v.y * v.y + v.z * v.z + v.w * v.w;
    int sk = (lane >> 3) + i * 8;
    size_t tb = ((size_t)p * NKT + sk) * 4096;
    write_split(AhP + tb, AlP + tb, rloc, kc, v);
  }
  #pragma unroll
  for (int o = 32; o > 0; o >>= 1) s += __shfl_xor(s, o, 64);
  if (lane == 0) xN[row] = s;
}

// ---------- P0b: codebook -> swizzled bf16 hi/lo panels + norms eN ----------
__global__ void k_prepB(const float* __restrict__ cb,
                        unsigned short* __restrict__ BhP, unsigned short* __restrict__ BlP,
                        float* __restrict__ eN) {
  int t = threadIdx.x, lane = t & 63, w = t >> 6;
  int row = blockIdx.x * 4 + w;
  const float* src = cb + (size_t)row * DIM;
  int p = row >> 7, rloc = row & 127;
  int kc = (lane & 7) * 4;
  float s = 0.f;
  #pragma unroll 8
  for (int i = 0; i < 64; ++i) {
    int kk = lane * 4 + i * 256;
    float4 v = *(const float4*)(src + kk);
    s += v.x * v.x + v.y * v.y + v.z * v.z + v.w * v.w;
    int sk = (lane >> 3) + i * 8;
    size_t tb = ((size_t)p * NKT + sk) * 4096;
    write_split(BhP + tb, BlP + tb, rloc, kc, v);
  }
  #pragma unroll
  for (int o = 32; o > 0; o >>= 1) s += __shfl_xor(s, o, 64);
  if (lane == 0) eN[row] = s;
}

// ---------- P0c: zero encodings + counts + loss ----------
__global__ void k_zero(float* __restrict__ enc, unsigned* __restrict__ counts,
                       double* __restrict__ lossA) {
  size_t i = (size_t)blockIdx.x * 256 + threadIdx.x;
  ((float4*)enc)[i] = make_float4(0.f, 0.f, 0.f, 0.f);
  if (blockIdx.x == 0) {
    counts[threadIdx.x] = 0u; counts[threadIdx.x + 256] = 0u;
    if (threadIdx.x == 0) *lossA = 0.0;
  }
}

// ---------- P2: bf16x3 GEMM, 2-phase double-buffered pipeline (T3-minimal) ----------
// grid (16 rb, 4 cblk, 16 kz) x 256 thr. Per step: STAGE(next) -> ds_read(cur)
// -> 48 MFMA -> vmcnt(0) -> barrier. One barrier per K-step; loads hide under MFMA.
__global__ __launch_bounds__(256, 2)
void k_gemm3(const unsigned short* __restrict__ AhP, const unsigned short* __restrict__ AlP,
             const unsigned short* __restrict__ BhP, const unsigned short* __restrict__ BlP,
             float* __restrict__ S) {
  __shared__ unsigned short AhS[8192], AlS[8192], BhS[8192], BlS[8192];  // 64 KB (2 bufs)
  int t = threadIdx.x, lane = t & 63, w = t >> 6;
  int rb = blockIdx.x, cblk = blockIdx.y, kz = blockIdx.z;
  int mBase = (w >> 1) * 64, nBase = (w & 1) * 64;
  int l15 = lane & 15, kByte = (lane >> 4) * 16;
  f32x4 acc[4][4] = {};

  size_t aBase = ((size_t)rb * NKT   + kz * 32) * 8192;  // bytes
  size_t bBase = ((size_t)cblk * NKT + kz * 32) * 8192;
  const char* aH = (const char*)AhP + aBase + t * 16;
  const char* aL = (const char*)AlP + aBase + t * 16;
  const char* bH = (const char*)BhP + bBase + t * 16;
  const char* bL = (const char*)BlP + bBase + t * 16;
  unsigned ldsOff = (unsigned)(w * 1024);  // wave-uniform

  // prologue: stage step 0 into buffer 0, drain, barrier
  gload16(aH,        (char*)AhS + ldsOff);
  gload16(aH + 4096, (char*)AhS + ldsOff + 4096);
  gload16(aL,        (char*)AlS + ldsOff);
  gload16(aL + 4096, (char*)AlS + ldsOff + 4096);
  gload16(bH,        (char*)BhS + ldsOff);
  gload16(bH + 4096, (char*)BhS + ldsOff + 4096);
  gload16(bL,        (char*)BlS + ldsOff);
  gload16(bL + 4096, (char*)BlS + ldsOff + 4096);
  asm volatile("s_waitcnt vmcnt(0)" ::: "memory");
  __builtin_amdgcn_s_barrier();
  __builtin_amdgcn_sched_barrier(0);

  #pragma unroll 2
  for (int s = 0; s < 32; ++s) {
    unsigned bo = (unsigned)(s & 1) << 13;    // current buffer byte offset
    unsigned bn = bo ^ 8192u;                 // next buffer
    if (s < 31) {                             // STAGE next tile (issue early)
      size_t go = (size_t)(s + 1) * 8192;
      gload16(aH + go,        (char*)AhS + bn + ldsOff);
      gload16(aH + go + 4096, (char*)AhS + bn + ldsOff + 4096);
      gload16(aL + go,        (char*)AlS + bn + ldsOff);
      gload16(aL + go + 4096, (char*)AlS + bn + ldsOff + 4096);
      gload16(bH + go,        (char*)BhS + bn + ldsOff);
      gload16(bH + go + 4096, (char*)BhS + bn + ldsOff + 4096);
      gload16(bL + go,        (char*)BlS + bn + ldsOff);
      gload16(bL + go + 4096, (char*)BlS + bn + ldsOff + 4096);
    }
    short8 ahf[4], alf[4], bhf[4], blf[4];
    #pragma unroll
    for (int m = 0; m < 4; ++m) {
      ahf[m] = *(const short8*)((const char*)AhS + bo + swz(mBase + m * 16 + l15, kByte));
      alf[m] = *(const short8*)((const char*)AlS + bo + swz(mBase + m * 16 + l15, kByte));
      bhf[m] = *(const short8*)((const char*)BhS + bo + swz(nBase + m * 16 + l15, kByte));
      blf[m] = *(const short8*)((const char*)BlS + bo + swz(nBase + m * 16 + l15, kByte));
    }
    __builtin_amdgcn_s_setprio(1);
    #pragma unroll
    for (int m = 0; m < 4; ++m) {
      #pragma unroll
      for (int n = 0; n < 4; ++n) {
        acc[m][n] = __builtin_amdgcn_mfma_f32_16x16x32_bf16(ahf[m], bhf[n], acc[m][n], 0, 0, 0);
        acc[m][n] = __builtin_amdgcn_mfma_f32_16x16x32_bf16(ahf[m], blf[n], acc[m][n], 0, 0, 0);
        acc[m][n] = __builtin_amdgcn_mfma_f32_16x16x32_bf16(alf[m], bhf[n], acc[m][n], 0, 0, 0);
      }
    }
    __builtin_amdgcn_s_setprio(0);
    asm volatile("s_waitcnt vmcnt(0)" ::: "memory");  // stage(next) landed
    __builtin_amdgcn_s_barrier();                     // all waves: cur consumed, next ready
    __builtin_amdgcn_sched_barrier(0);
  }

  int r0v = (lane >> 4) * 4;
  float* Sb = S + (size_t)kz * NB * NE;
  #pragma unroll
  for (int m = 0; m < 4; ++m) {
    int gr = rb * 128 + mBase + m * 16 + r0v;
    #pragma unroll
    for (int n = 0; n < 4; ++n) {
      int gc = cblk * 128 + nBase + n * 16 + l15;
      #pragma unroll
      for (int r = 0; r < 4; ++r)
        Sb[(size_t)(gr + r) * NE + gc] = -2.0f * acc[m][n][r];
    }
  }
}

// ---------- P3: argmin over split-reduced dist + hist + one-hot + loss ----------
__global__ void k_argmin_split(const float* __restrict__ S, const float* __restrict__ eN,
                               const float* __restrict__ xN, int* __restrict__ idx,
                               unsigned* __restrict__ counts, float* __restrict__ enc,
                               double* __restrict__ lossA) {
  int w = threadIdx.x >> 6, lane = threadIdx.x & 63;
  int r = blockIdx.x * 4 + w;
  float bd = 3.4e38f; int bj = 0;
  #pragma unroll
  for (int i = 0; i < 8; ++i) {
    int j = i * 64 + lane;
    float d = eN[j];
    #pragma unroll
    for (int kz = 0; kz < SPLITS; ++kz)
      d += S[((size_t)kz * NB + r) * NE + j];
    if (d < bd) { bd = d; bj = j; }
  }
  #pragma unroll
  for (int o = 32; o > 0; o >>= 1) {
    float od = __shfl_xor(bd, o, 64);
    int   oj = __shfl_xor(bj, o, 64);
    if (od < bd || (od == bd && oj < bj)) { bd = od; bj = oj; }
  }
  if (lane == 0) {
    idx[r] = bj;
    atomicAdd(&counts[bj], 1u);
    enc[(size_t)r * NE + bj] = 1.0f;
    atomicAdd(lossA, (double)(xN[r] + bd));   // ||x-e||^2 = ||x||^2 + (||e||^2 - 2x.e)
  }
}

// ---------- P4: pure gather codebook row -> output ----------
__global__ void k_gather2(const float* __restrict__ cbk, const int* __restrict__ idx,
                          float* __restrict__ outq) {
  int r = blockIdx.x, t = threadIdx.x;
  int ci = idx[r];
  const float4* q = (const float4*)(cbk + (size_t)ci * DIM);
  float4* o = (float4*)(outq + (size_t)r * DIM);
  #pragma unroll
  for (int i = 0; i < 16; ++i) o[t + i * 256] = q[t + i * 256];
}

__global__ void k_final(const unsigned* __restrict__ counts,
                        const double* __restrict__ lossA,
                        float* __restrict__ outLoss, float* __restrict__ outPerp) {
  int t = threadIdx.x;
  float h = 0.f;
  #pragma unroll
  for (int i = 0; i < 2; ++i) {
    float p = (float)counts[t + i * 256] * (1.0f / 2048.0f);
    h += p * logf(p + 1e-10f);
  }
  h = blockReduceSum(h);
  if (t == 0) {
    *outLoss = 1.25f * (float)(*lossA * (1.0 / (double)NQ));
    *outPerp = expf(-h);
  }
}

// =================== FALLBACK PATH (round-1, ~4.2 MB ws) ===================

__global__ void k_init(const float* __restrict__ cb, float* __restrict__ S,
                       float* __restrict__ eN, float* __restrict__ enc,
                       unsigned* __restrict__ counts, double* __restrict__ lossA) {
  int j = blockIdx.x, t = threadIdx.x;
  const float* row = cb + (size_t)j * DIM;
  float s = 0.f;
  #pragma unroll
  for (int i = 0; i < 16; ++i) {
    float4 v = *(const float4*)(row + i * 1024 + t * 4);
    s += v.x * v.x + v.y * v.y + v.z * v.z + v.w * v.w;
  }
  s = blockReduceSum(s);
  if (t == 0) eN[j] = s;
  float4 z = make_float4(0.f, 0.f, 0.f, 0.f);
  float4* Sp = (float4*)(S + (size_t)j * 2048);
  float4* Ep = (float4*)(enc + (size_t)j * 2048);
  Sp[t] = z; Sp[t + 256] = z;
  Ep[t] = z; Ep[t + 256] = z;
  if (j == 0) {
    counts[t] = 0u; counts[t + 256] = 0u;
    if (t == 0) *lossA = 0.0;
  }
}

__global__ __launch_bounds__(256, 2)
void k_gemm(const float* __restrict__ A, const float* __restrict__ Bc,
            float* __restrict__ S) {
  __shared__ unsigned short AsHi[128 * 32], AsLo[128 * 32];
  __shared__ unsigned short BsHi[128 * 32], BsLo[128 * 32];
  int t = threadIdx.x;
  int lane = t & 63, w = t >> 6;
  int rb = blockIdx.x, cblk = blockIdx.y, kz = blockIdx.z;
  int mBase = (w >> 1) * 64, nBase = (w & 1) * 64;
  int l15 = lane & 15, kByte = (lane >> 4) * 16;
  f32x4 acc[4][4] = {};
  int arow = t >> 3;
  int kc = (t & 7) * 4;
  const float* Abase = A + (size_t)(rb * 128) * DIM + kz * 2048 + kc;
  const float* Bbase = Bc + (size_t)(cblk * 128) * DIM + kz * 2048 + kc;

  for (int s = 0; s < 64; ++s) {
    __syncthreads();
    #pragma unroll
    for (int i = 0; i < 4; ++i) {
      int row = arow + i * 32;
      float4 av = *(const float4*)(Abase + (size_t)row * DIM + s * 32);
      write_split(AsHi, AsLo, row, kc, av);
      float4 bv = *(const float4*)(Bbase + (size_t)row * DIM + s * 32);
      write_split(BsHi, BsLo, row, kc, bv);
    }
    __syncthreads();
    short8 ah[4], al[4], bh[4], bl[4];
    #pragma unroll
    for (int m = 0; m < 4; ++m) {
      ah[m] = *(const short8*)((const char*)AsHi + swz(mBase + m * 16 + l15, kByte));
      al[m] = *(const short8*)((const char*)AsLo + swz(mBase + m * 16 + l15, kByte));
      bh[m] = *(const short8*)((const char*)BsHi + swz(nBase + m * 16 + l15, kByte));
      bl[m] = *(const short8*)((const char*)BsLo + swz(nBase + m * 16 + l15, kByte));
    }
    #pragma unroll
    for (int m = 0; m < 4; ++m) {
      #pragma unroll
      for (int n = 0; n < 4; ++n) {
        acc[m][n] = __builtin_amdgcn_mfma_f32_16x16x32_bf16(ah[m], bh[n], acc[m][n], 0, 0, 0);
        acc[m][n] = __builtin_amdgcn_mfma_f32_16x16x32_bf16(ah[m], bl[n], acc[m][n], 0, 0, 0);
        acc[m][n] = __builtin_amdgcn_mfma_f32_16x16x32_bf16(al[m], bh[n], acc[m][n], 0, 0, 0);
      }
    }
  }
  int r0 = (lane >> 4) * 4;
  #pragma unroll
  for (int m = 0; m < 4; ++m) {
    int gr = rb * 128 + mBase + m * 16 + r0;
    #pragma unroll
    for (int n = 0; n < 4; ++n) {
      int gc = cblk * 128 + nBase + n * 16 + l15;
      #pragma unroll
      for (int r = 0; r < 4; ++r)
        atomicAdd(&S[(size_t)(gr + r) * NE + gc], -2.0f * acc[m][n][r]);
    }
  }
}

__global__ void k_argmin_flat(const float* __restrict__ S, const float* __restrict__ eN,
                              int* __restrict__ idx, unsigned* __restrict__ counts) {
  int w = threadIdx.x >> 6, lane = threadIdx.x & 63;
  int r = blockIdx.x * 4 + w;
  const float* Sr = S + (size_t)r * NE;
  float bd = 3.4e38f; int bj = 0;
  #pragma unroll
  for (int i = 0; i < 8; ++i) {
    int j = i * 64 + lane;
    float d = eN[j] + Sr[j];
    if (d < bd) { bd = d; bj = j; }
  }
  #pragma unroll
  for (int o = 32; o > 0; o >>= 1) {
    float od = __shfl_xor(bd, o, 64);
    int   oj = __shfl_xor(bj, o, 64);
    if (od < bd || (od == bd && oj < bj)) { bd = od; bj = oj; }
  }
  if (lane == 0) { idx[r] = bj; atomicAdd(&counts[bj], 1u); }
}

__global__ void k_gather(const float* __restrict__ x, const float* __restrict__ cbk,
                         const int* __restrict__ idx, float* __restrict__ outq,
                         float* __restrict__ enc, double* __restrict__ lossA) {
  int r = blockIdx.x, t = threadIdx.x;
  int ci = idx[r];
  const float* q  = cbk + (size_t)ci * DIM;
  const float* xr = x + (size_t)r * DIM;
  float* o = outq + (size_t)r * DIM;
  float s = 0.f;
  #pragma unroll
  for (int i = 0; i < 16; ++i) {
    int off = i * 1024 + t * 4;
    float4 qv = *(const float4*)(q + off);
    float4 xv = *(const float4*)(xr + off);
    *(float4*)(o + off) = qv;
    float dx = qv.x - xv.x, dy = qv.y - xv.y;
    float dz = qv.z - xv.z, dw = qv.w - xv.w;
    s += dx * dx + dy * dy + dz * dz + dw * dw;
  }
  s = blockReduceSum(s);
  if (t == 0) {
    atomicAdd(lossA, (double)s);
    enc[(size_t)r * NE + ci] = 1.0f;
  }
}

extern "C" void kernel_launch(void* const* d_in, const int* in_sizes, int n_in,
                              void* d_out, int out_size, void* d_ws, size_t ws_size,
                              hipStream_t stream) {
  (void)in_sizes; (void)n_in; (void)out_size;
  const float* x  = (const float*)d_in[0];
  const float* cb = (const float*)d_in[1];

  float* out     = (float*)d_out;
  float* outLoss = out;
  float* outQ    = out + 1;
  float* outPerp = out + 1 + NQ;
  float* outEnc  = out + 2 + NQ;

  char* ws = (char*)d_ws;

  const size_t oAh = 0;
  const size_t oAl = 67108864;            // 64 MB
  const size_t oBh = 134217728;           // 128 MB
  const size_t oBl = 150994944;           // 144 MB
  const size_t oS  = 167772160;           // 160 MB (16 x 4 MB)
  const size_t oEN = 234881024;           // 224 MB
  const size_t oXN  = oEN + 2048;
  const size_t oIDX = oXN + 8192;
  const size_t oCNT = oIDX + 8192;
  const size_t oLOSS = oCNT + 2048;
  const size_t NEED = oLOSS + 8;

  if (ws_size >= NEED) {
    unsigned short* AhP = (unsigned short*)(ws + oAh);
    unsigned short* AlP = (unsigned short*)(ws + oAl);
    unsigned short* BhP = (unsigned short*)(ws + oBh);
    unsigned short* BlP = (unsigned short*)(ws + oBl);
    float*    S      = (float*)(ws + oS);
    float*    eN     = (float*)(ws + oEN);
    float*    xN     = (float*)(ws + oXN);
    int*      idx    = (int*)(ws + oIDX);
    unsigned* counts = (unsigned*)(ws + oCNT);
    double*   lossA  = (double*)(ws + oLOSS);

    k_prepA<<<NB / 4, 256, 0, stream>>>(x, AhP, AlP, xN);
    k_prepB<<<NE / 4, 256, 0, stream>>>(cb, BhP, BlP, eN);
    k_zero <<<NENC / 1024, 256, 0, stream>>>(outEnc, counts, lossA);
    k_gemm3<<<dim3(16, 4, SPLITS), 256, 0, stream>>>(AhP, AlP, BhP, BlP, S);
    k_argmin_split<<<NB / 4, 256, 0, stream>>>(S, eN, xN, idx, counts, outEnc, lossA);
    k_gather2<<<NB, 256, 0, stream>>>(cb, idx, outQ);
    k_final<<<1, 256, 0, stream>>>(counts, lossA, outLoss, outPerp);
  } else {
    float*    S      = (float*)ws;
    float*    eN     = (float*)(ws + 4194304);
    int*      idx    = (int*)(ws + 4196352);
    unsigned* counts = (unsigned*)(ws + 4204544);
    double*   lossA  = (double*)(ws + 4206592);

    k_init  <<<NE, 256, 0, stream>>>(cb, S, eN, outEnc, counts, lossA);
    k_gemm  <<<dim3(16, 4, 8), 256, 0, stream>>>(x, cb, S);
    k_argmin_flat<<<NB / 4, 256, 0, stream>>>(S, eN, idx, counts);
    k_gather<<<NB, 256, 0, stream>>>(x, cb, idx, outQ, outEnc, lossA);
    k_final <<<1, 256, 0, stream>>>(counts, lossA, outLoss, outPerp);
  }
}